// Round 1
// baseline (469.594 us; speedup 1.0000x reference)
//
#include <hip/hip_runtime.h>
#include <hip/hip_bf16.h>

// Problem constants (from reference setup_inputs):
//   B=8, T=4096, x0:[8,1024,4096] f32, x1:[8,768,4096] f32
//   BC=256, RC=64, NB0=4, NB1=3, TB=7, EPS=1e-5, LOWEST=0
#define B_SZ 8
#define T_SZ 4096
#define BC 256
#define RC 64
#define NB0 4
#define NB1 3
#define TB 7
#define ROWS0 (B_SZ * 1024)            // 8192 rows in x0
#define ROWS1 (B_SZ * 768)             // 6144 rows in x1
#define ROWS_TOTAL (ROWS0 + ROWS1)     // 14336
#define X0_ELEMS (33554432ull)         // 8*1024*4096

// ---------------------------------------------------------------------------
// Kernel 1: per-row sum over time, accumulate into gap[b*256+c] via atomicAdd.
// One wave (64 lanes) per row of 4096 floats = 1024 float4 = 16 float4/lane.
// blockDim = 256 -> 4 rows per block; grid = 14336/4 = 3584 blocks.
// ---------------------------------------------------------------------------
__global__ __launch_bounds__(256) void gap_kernel(const float* __restrict__ x0,
                                                  const float* __restrict__ x1,
                                                  float* __restrict__ gap) {
    const int gtid = blockIdx.x * blockDim.x + threadIdx.x;
    const int wave = gtid >> 6;        // global row index
    const int lane = threadIdx.x & 63;

    const float4* src;
    int b, c;
    if (wave < ROWS0) {
        b = wave >> 10;                 // /1024
        const int ch = wave & 1023;
        c = ch & 255;
        src = (const float4*)(x0 + (size_t)wave * T_SZ);
    } else {
        const int r = wave - ROWS0;
        b = r / 768;
        const int ch = r - b * 768;
        c = ch & 255;
        src = (const float4*)(x1 + (size_t)r * T_SZ);
    }

    float sum = 0.0f;
#pragma unroll
    for (int it = 0; it < 16; ++it) {
        float4 v = src[it * 64 + lane];
        sum += (v.x + v.y) + (v.z + v.w);
    }
    // wave-64 butterfly reduce
#pragma unroll
    for (int off = 32; off > 0; off >>= 1)
        sum += __shfl_down(sum, off, 64);

    if (lane == 0)
        atomicAdd(gap + b * BC + c, sum * (1.0f / (float)T_SZ));
}

// ---------------------------------------------------------------------------
// Kernel 2: tiny attention math, one block of 256 threads.
//   h[b,r]   = relu((gap[b,:] @ W1[:,r] + b1[r]) * gamma[r]/sqrt(1+eps) + beta[r])
//   s[k,b,c] = h[b,:] @ Wh[k,:,c] + bh[k,c]
//   att[b,k,c] = softmax_k(s)  (LOWEST=0 so no affine remap)
// ---------------------------------------------------------------------------
__global__ __launch_bounds__(256) void attn_kernel(const float* __restrict__ gap,
                                                   const float* __restrict__ W1,
                                                   const float* __restrict__ b1,
                                                   const float* __restrict__ gamma,
                                                   const float* __restrict__ beta,
                                                   const float* __restrict__ Wh,
                                                   const float* __restrict__ bh,
                                                   float* __restrict__ att) {
    __shared__ float s_gap[B_SZ][BC];
    __shared__ float s_h[B_SZ][RC];
    const int tid = threadIdx.x;

#pragma unroll
    for (int b = 0; b < B_SZ; ++b)
        s_gap[b][tid] = gap[b * BC + tid];
    __syncthreads();

    const float bnscale = rsqrtf(1.0f + 1e-5f);
    // 512 (b,r) dot products of length 256 -> 2 per thread
    for (int p = tid; p < B_SZ * RC; p += 256) {
        const int b = p >> 6;
        const int r = p & 63;
        float acc = 0.0f;
        for (int c = 0; c < BC; ++c)
            acc = fmaf(s_gap[b][c], W1[c * RC + r], acc);
        acc += b1[r];
        acc = acc * (gamma[r] * bnscale) + beta[r];
        s_h[b][r] = fmaxf(acc, 0.0f);
    }
    __syncthreads();

    // thread tid handles channel c = tid for all (k,b)
    float sc[TB];
#pragma unroll 1
    for (int b = 0; b < B_SZ; ++b) {
        float mx = -1e30f;
#pragma unroll
        for (int k = 0; k < TB; ++k) {
            float acc = bh[k * BC + tid];
            for (int r = 0; r < RC; ++r)
                acc = fmaf(s_h[b][r], Wh[(k * RC + r) * BC + tid], acc);
            sc[k] = acc;
            mx = fmaxf(mx, acc);
        }
        float sum = 0.0f;
#pragma unroll
        for (int k = 0; k < TB; ++k) {
            sc[k] = __expf(sc[k] - mx);
            sum += sc[k];
        }
        const float inv = 1.0f / sum;
#pragma unroll
        for (int k = 0; k < TB; ++k)
            att[(b * TB + k) * BC + tid] = sc[k] * inv;
    }
}

// ---------------------------------------------------------------------------
// Kernel 3: scale each row by its attention scalar. One block per row,
// 256 threads x 4 float4 = 4096 floats.
// d_out = [out0 flat (33.5M) | out1 flat (25.2M)]
// ---------------------------------------------------------------------------
__global__ __launch_bounds__(256) void scale_kernel(const float* __restrict__ x0,
                                                    const float* __restrict__ x1,
                                                    const float* __restrict__ att,
                                                    float* __restrict__ out) {
    const int row = blockIdx.x;
    const float4* src;
    float4* dst;
    float a;
    if (row < ROWS0) {
        const int b = row >> 10;
        const int ch = row & 1023;
        a = att[(b * TB + (ch >> 8)) * BC + (ch & 255)];
        src = (const float4*)(x0 + (size_t)row * T_SZ);
        dst = (float4*)(out + (size_t)row * T_SZ);
    } else {
        const int r = row - ROWS0;
        const int b = r / 768;
        const int ch = r - b * 768;
        a = att[(b * TB + NB0 + (ch >> 8)) * BC + (ch & 255)];
        src = (const float4*)(x1 + (size_t)r * T_SZ);
        dst = (float4*)(out + X0_ELEMS + (size_t)r * T_SZ);
    }
    const int tid = threadIdx.x;
#pragma unroll
    for (int it = 0; it < 4; ++it) {
        float4 v = src[it * 256 + tid];
        v.x *= a; v.y *= a; v.z *= a; v.w *= a;
        dst[it * 256 + tid] = v;
    }
}

extern "C" void kernel_launch(void* const* d_in, const int* in_sizes, int n_in,
                              void* d_out, int out_size, void* d_ws, size_t ws_size,
                              hipStream_t stream) {
    const float* x0    = (const float*)d_in[0];
    const float* x1    = (const float*)d_in[1];
    const float* W1    = (const float*)d_in[2];
    const float* b1    = (const float*)d_in[3];
    const float* gamma = (const float*)d_in[4];
    const float* beta  = (const float*)d_in[5];
    const float* Wh    = (const float*)d_in[6];
    const float* bh    = (const float*)d_in[7];
    float* out = (float*)d_out;

    float* gap = (float*)d_ws;              // 2048 floats (8 KiB)
    float* att = gap + 2048;                // 14336 floats (56 KiB)

    // gap accumulator must start at zero (ws is poisoned 0xAA each call)
    hipMemsetAsync(gap, 0, B_SZ * BC * sizeof(float), stream);

    gap_kernel<<<ROWS_TOTAL / 4, 256, 0, stream>>>(x0, x1, gap);
    attn_kernel<<<1, 256, 0, stream>>>(gap, W1, b1, gamma, beta, Wh, bh, att);
    scale_kernel<<<ROWS_TOTAL, 256, 0, stream>>>(x0, x1, att, out);
}